// Round 1
// baseline (1397.849 us; speedup 1.0000x reference)
//
#include <hip/hip_runtime.h>

constexpr int N = 8192;
constexpr int D = 64;
constexpr int E = 524288;

// ---------------- workspace layout (bytes) ----------------
constexpr size_t SZ_BITMAP = (size_t)N * (size_t)N / 8;   // 8,388,608
constexpr size_t SZ_CNT    = 8256 * sizeof(int);          // 33,024 (>= (N+1)*4)
constexpr size_t O_BITMAP  = 0;
constexpr size_t O_SRCCNT  = O_BITMAP + SZ_BITMAP;
constexpr size_t O_DSTCNT  = O_SRCCNT + SZ_CNT;
constexpr size_t O_NF1     = O_DSTCNT + SZ_CNT;
constexpr size_t O_NF2     = O_NF1 + N;
constexpr size_t O_POOLED  = O_NF2 + N;                   // 192 floats used
constexpr size_t ZERO_END  = O_POOLED + 1024;             // memset [0, ZERO_END)
constexpr size_t O_SRCPTR  = ZERO_END;
constexpr size_t O_DSTPTR  = O_SRCPTR + SZ_CNT;
constexpr size_t O_SRCFILL = O_DSTPTR + SZ_CNT;
constexpr size_t O_DSTFILL = O_SRCFILL + SZ_CNT;
constexpr size_t O_EFLAGS  = O_DSTFILL + SZ_CNT;          // E bytes
constexpr size_t O_CSRS    = O_EFLAGS + (size_t)E;
constexpr size_t O_CSRD    = O_CSRS + (size_t)E * 4;
constexpr size_t O_AH      = O_CSRD + (size_t)E * 4;
constexpr size_t O_Z       = O_AH + (size_t)N * D * 4;
constexpr size_t O_AZ1     = O_Z + (size_t)N * D * 4;
constexpr size_t O_AZ2     = O_AZ1 + (size_t)N * D * 4;
constexpr size_t O_FT      = O_AZ2 + (size_t)N * D * 4;   // reused per motif

// ---------------- kernels ----------------

// Per-edge: dedupe ownership via bitmap atomicOr, gather motif masks from
// dense A1/A2, count degrees for the two CSRs, flag motif endpoint nodes.
__global__ void edge_classify(const int* __restrict__ src, const int* __restrict__ dst,
                              const float* __restrict__ A1, const float* __restrict__ A2,
                              unsigned* __restrict__ bitmap,
                              int* __restrict__ srcCnt, int* __restrict__ dstCnt,
                              unsigned char* __restrict__ nf1, unsigned char* __restrict__ nf2,
                              unsigned char* __restrict__ eflags) {
    int i = blockIdx.x * blockDim.x + threadIdx.x;
    if (i >= E) return;
    int u = src[i], v = dst[i];
    long long key = ((long long)u << 13) | v;
    unsigned bit = 1u << (key & 31);
    unsigned old = atomicOr(&bitmap[key >> 5], bit);
    int own = ((old & bit) == 0) ? 1 : 0;
    float a1 = A1[key];
    float a2 = A2[key];
    int f1 = (a1 > 0.0f) ? 1 : 0;
    int f2 = (a2 > 0.0f) ? 1 : 0;
    eflags[i] = (unsigned char)(own | (f1 << 1) | (f2 << 2));
    if (own) atomicAdd(&srcCnt[u], 1);
    atomicAdd(&dstCnt[v], 1);
    if (f1) { nf1[u] = 1; nf1[v] = 1; }
    if (f2) { nf2[u] = 1; nf2[v] = 1; }
}

// Exclusive prefix scan of 8192 counts (one block per array).
__global__ void scan2(const int* __restrict__ srcCnt, int* __restrict__ srcPtr, int* __restrict__ srcFill,
                      const int* __restrict__ dstCnt, int* __restrict__ dstPtr, int* __restrict__ dstFill) {
    const int* cnt = (blockIdx.x == 0) ? srcCnt : dstCnt;
    int* ptr  = (blockIdx.x == 0) ? srcPtr : dstPtr;
    int* fill = (blockIdx.x == 0) ? srcFill : dstFill;
    __shared__ int ssum[256];
    int t = threadIdx.x;
    int base = t * 32;
    int loc[32];
    int s = 0;
    for (int j = 0; j < 32; ++j) { loc[j] = cnt[base + j]; s += loc[j]; }
    ssum[t] = s;
    __syncthreads();
    for (int off = 1; off < 256; off <<= 1) {
        int v = (t >= off) ? ssum[t - off] : 0;
        __syncthreads();
        ssum[t] += v;
        __syncthreads();
    }
    int ex = (t == 0) ? 0 : ssum[t - 1];
    for (int j = 0; j < 32; ++j) {
        ptr[base + j] = ex;
        fill[base + j] = ex;
        ex += loc[j];
    }
    if (t == 255) ptr[N] = ex;
}

// Scatter edges into src-CSR (owned only, dst+flags packed) and dst-CSR (all, src+flags).
__global__ void csr_fill(const int* __restrict__ src, const int* __restrict__ dst,
                         const unsigned char* __restrict__ eflags,
                         int* __restrict__ srcFill, int* __restrict__ dstFill,
                         int* __restrict__ csrS, int* __restrict__ csrD) {
    int i = blockIdx.x * blockDim.x + threadIdx.x;
    if (i >= E) return;
    int u = src[i], v = dst[i];
    int fl = eflags[i];
    int f12 = (fl >> 1) & 3;
    if (fl & 1) {
        int p = atomicAdd(&srcFill[u], 1);
        csrS[p] = v | (f12 << 13);
    }
    int p2 = atomicAdd(&dstFill[v], 1);
    csrD[p2] = u | (f12 << 13);
}

// Ah = A @ h over deduped edges. One wave per row, lane = feature.
__global__ void spmm_base(const int* __restrict__ srcPtr, const int* __restrict__ csrS,
                          const float* __restrict__ h, float* __restrict__ Ah) {
    int wid = threadIdx.x >> 6, lane = threadIdx.x & 63;
    int row = blockIdx.x * 4 + wid;
    if (row >= N) return;
    int b = srcPtr[row], e = srcPtr[row + 1];
    float acc = 0.0f;
    for (int j = b; j < e; ++j) {
        int v = csrS[j] & 8191;
        acc += h[(size_t)v * D + lane];
    }
    Ah[(size_t)row * D + lane] = acc;
}

// az1 = A1 @ Z, az2 = A2 @ Z in one pass (flags select contribution).
__global__ void spmm_motifs(const int* __restrict__ srcPtr, const int* __restrict__ csrS,
                            const float* __restrict__ Z,
                            float* __restrict__ az1, float* __restrict__ az2) {
    int wid = threadIdx.x >> 6, lane = threadIdx.x & 63;
    int row = blockIdx.x * 4 + wid;
    if (row >= N) return;
    int b = srcPtr[row], e = srcPtr[row + 1];
    float a1 = 0.0f, a2 = 0.0f;
    for (int j = b; j < e; ++j) {
        int ent = csrS[j];
        if ((ent >> 13) == 0) continue;
        float z = Z[(size_t)(ent & 8191) * D + lane];
        if (ent & (1 << 13)) a1 += z;
        if (ent & (1 << 14)) a2 += z;
    }
    az1[(size_t)row * D + lane] = a1;
    az2[(size_t)row * D + lane] = a2;
}

// Y[N,64] = X[N,64] @ W (or W^T) + optional bias. Wave per row via shfl broadcast.
__global__ void gemm64(const float* __restrict__ X, const float* __restrict__ W,
                       const float* __restrict__ bias, float* __restrict__ Y, int transW) {
    __shared__ float Wl[64 * 64];
    int t = threadIdx.x;
    for (int i = t; i < 4096; i += 256) {
        int r = i >> 6, c = i & 63;            // Wl[k=r][j=c]
        Wl[i] = transW ? W[c * 64 + r] : W[i]; // trans: Wl[k][j] = W[j][k]
    }
    __syncthreads();
    int wid = t >> 6, lane = t & 63;
    for (int row = blockIdx.x * 4 + wid; row < N; row += gridDim.x * 4) {
        float x = X[(size_t)row * D + lane];
        float acc = bias ? bias[lane] : 0.0f;
        for (int k = 0; k < 64; ++k) {
            float bv = __shfl(x, k);
            acc = fmaf(bv, Wl[k * 64 + lane], acc);
        }
        Y[(size_t)row * D + lane] = acc;
    }
}

// Fused edge-softmax + aggregate + pool for one motif over dst-CSR (ALL edges).
// maskBit: 0 = no mask (motif 0), else bit index (13 or 14) in csrD entries.
__global__ void gat_pool(const float* __restrict__ ft,
                         const int* __restrict__ dstPtr, const int* __restrict__ csrD,
                         float* __restrict__ pooled, int maskBit) {
    int t = threadIdx.x;
    int wid = t >> 6, lane = t & 63;
    float pool = 0.0f;
    for (int row = blockIdx.x * 4 + wid; row < N; row += gridDim.x * 4) {
        float ftv = ft[(size_t)row * D + lane];
        int b = dstPtr[row], e = dstPtr[row + 1];
        float m = -3.0e38f;
        for (int j = b; j < e; ++j) {
            int ent = csrD[j];
            if (maskBit && !((ent >> maskBit) & 1)) continue;
            int u = ent & 8191;
            float x = ft[(size_t)u * D + lane];
            float p = x * ftv;
            p += __shfl_xor(p, 1);  p += __shfl_xor(p, 2);  p += __shfl_xor(p, 4);
            p += __shfl_xor(p, 8);  p += __shfl_xor(p, 16); p += __shfl_xor(p, 32);
            m = fmaxf(m, p * 0.125f);
        }
        float den = 0.0f, acc = 0.0f;
        for (int j = b; j < e; ++j) {
            int ent = csrD[j];
            if (maskBit && !((ent >> maskBit) & 1)) continue;
            int u = ent & 8191;
            float x = ft[(size_t)u * D + lane];
            float p = x * ftv;
            p += __shfl_xor(p, 1);  p += __shfl_xor(p, 2);  p += __shfl_xor(p, 4);
            p += __shfl_xor(p, 8);  p += __shfl_xor(p, 16); p += __shfl_xor(p, 32);
            float w = expf(p * 0.125f - m);
            den += w;
            acc = fmaf(w, x, acc);
        }
        pool += acc / fmaxf(den, 1e-9f);
    }
    __shared__ float red[256];
    red[t] = pool;
    __syncthreads();
    if (wid == 0) {
        float s = red[lane] + red[64 + lane] + red[128 + lane] + red[192 + lane];
        atomicAdd(&pooled[lane], s);
    }
}

// Final: motif node counts, divide pooled sums, 192x2 linear.
__global__ void final_kernel(const float* __restrict__ pooled,
                             const unsigned char* __restrict__ nf1, const unsigned char* __restrict__ nf2,
                             const float* __restrict__ lin_w, const float* __restrict__ lin_b,
                             float* __restrict__ out) {
    __shared__ int r1[256], r2[256];
    __shared__ float feat[192];
    __shared__ int cnt[2];
    int t = threadIdx.x;
    int s1 = 0, s2 = 0;
    for (int i = t; i < N; i += 256) { s1 += nf1[i]; s2 += nf2[i]; }
    r1[t] = s1; r2[t] = s2;
    __syncthreads();
    for (int off = 128; off > 0; off >>= 1) {
        if (t < off) { r1[t] += r1[t + off]; r2[t] += r2[t + off]; }
        __syncthreads();
    }
    if (t == 0) { cnt[0] = r1[0]; cnt[1] = r2[0]; }
    __syncthreads();
    if (t < 192) {
        int sel = t >> 6;
        float div = (sel == 0) ? (float)N : fmaxf((float)cnt[sel - 1], 1.0f);
        feat[t] = pooled[t] / div;
    }
    __syncthreads();
    if (t < 2) {
        float o = lin_b[t];
        for (int k = 0; k < 192; ++k) o = fmaf(feat[k], lin_w[k * 2 + t], o);
        out[t] = o;
    }
}

// ---------------- launch ----------------
extern "C" void kernel_launch(void* const* d_in, const int* in_sizes, int n_in,
                              void* d_out, int out_size, void* d_ws, size_t ws_size,
                              hipStream_t stream) {
    const float* h   = (const float*)d_in[0];
    // d_in[1] (dense A) is never needed: its structure == edge list, values == 1.
    const float* A1  = (const float*)d_in[2];
    const float* A2  = (const float*)d_in[3];
    const float* Ww  = (const float*)d_in[4];
    const float* Wb  = (const float*)d_in[5];
    const float* fc0 = (const float*)d_in[6];
    const float* fc1 = (const float*)d_in[7];
    const float* fc2 = (const float*)d_in[8];
    const float* lw  = (const float*)d_in[9];
    const float* lb  = (const float*)d_in[10];
    const int* src   = (const int*)d_in[11];
    const int* dst   = (const int*)d_in[12];
    float* out = (float*)d_out;

    char* w = (char*)d_ws;
    unsigned* bitmap   = (unsigned*)(w + O_BITMAP);
    int* srcCnt        = (int*)(w + O_SRCCNT);
    int* dstCnt        = (int*)(w + O_DSTCNT);
    unsigned char* nf1 = (unsigned char*)(w + O_NF1);
    unsigned char* nf2 = (unsigned char*)(w + O_NF2);
    float* pooled      = (float*)(w + O_POOLED);
    int* srcPtr        = (int*)(w + O_SRCPTR);
    int* dstPtr        = (int*)(w + O_DSTPTR);
    int* srcFill       = (int*)(w + O_SRCFILL);
    int* dstFill       = (int*)(w + O_DSTFILL);
    unsigned char* efl = (unsigned char*)(w + O_EFLAGS);
    int* csrS          = (int*)(w + O_CSRS);
    int* csrD          = (int*)(w + O_CSRD);
    float* Ah          = (float*)(w + O_AH);
    float* Z           = (float*)(w + O_Z);
    float* az1         = (float*)(w + O_AZ1);
    float* az2         = (float*)(w + O_AZ2);
    float* ft          = (float*)(w + O_FT);

    hipMemsetAsync(w, 0, ZERO_END, stream);

    edge_classify<<<E / 256, 256, 0, stream>>>(src, dst, A1, A2, bitmap, srcCnt, dstCnt, nf1, nf2, efl);
    scan2<<<2, 256, 0, stream>>>(srcCnt, srcPtr, srcFill, dstCnt, dstPtr, dstFill);
    csr_fill<<<E / 256, 256, 0, stream>>>(src, dst, efl, srcFill, dstFill, csrS, csrD);

    spmm_base<<<N / 4, 256, 0, stream>>>(srcPtr, csrS, h, Ah);
    gemm64<<<512, 256, 0, stream>>>(Ah, Ww, Wb, Z, 1);            // Z = Ah @ Ww^T + Wb
    spmm_motifs<<<N / 4, 256, 0, stream>>>(srcPtr, csrS, Z, az1, az2);

    gemm64<<<512, 256, 0, stream>>>(Z, fc0, nullptr, ft, 0);      // ft0 = Z @ fc0
    gat_pool<<<512, 256, 0, stream>>>(ft, dstPtr, csrD, pooled + 0, 0);

    gemm64<<<512, 256, 0, stream>>>(az1, fc1, nullptr, ft, 0);    // ft1 = az1 @ fc1
    gat_pool<<<512, 256, 0, stream>>>(ft, dstPtr, csrD, pooled + 64, 13);

    gemm64<<<512, 256, 0, stream>>>(az2, fc2, nullptr, ft, 0);    // ft2 = az2 @ fc2
    gat_pool<<<512, 256, 0, stream>>>(ft, dstPtr, csrD, pooled + 128, 14);

    final_kernel<<<1, 256, 0, stream>>>(pooled, nf1, nf2, lw, lb, out);
}

// Round 2
// 1016.847 us; speedup vs baseline: 1.3747x; 1.3747x over previous
//
#include <hip/hip_runtime.h>

constexpr int N = 8192;
constexpr int D = 64;
constexpr int E = 524288;

// ---------------- workspace layout (bytes) ----------------
constexpr size_t SZ_BITMAP = (size_t)N * (size_t)N / 8;   // 8,388,608
constexpr size_t SZ_CNT    = 8256 * sizeof(int);          // >= (N+1)*4
constexpr size_t O_BITMAP  = 0;
constexpr size_t O_SRCCNT  = O_BITMAP + SZ_BITMAP;
constexpr size_t O_DSTCNT  = O_SRCCNT + SZ_CNT;
constexpr size_t O_NF1     = O_DSTCNT + SZ_CNT;
constexpr size_t O_NF2     = O_NF1 + N;
constexpr size_t O_POOLED  = O_NF2 + N;                   // 192 floats used
constexpr size_t ZERO_END  = O_POOLED + 1024;             // memset [0, ZERO_END)
constexpr size_t O_SRCPTR  = ZERO_END;
constexpr size_t O_DSTPTR  = O_SRCPTR + SZ_CNT;
constexpr size_t O_SRCFILL = O_DSTPTR + SZ_CNT;
constexpr size_t O_DSTFILL = O_SRCFILL + SZ_CNT;
constexpr size_t O_EFLAGS  = O_DSTFILL + SZ_CNT;          // E bytes
constexpr size_t O_CSRS    = O_EFLAGS + (size_t)E;
constexpr size_t O_CSRD    = O_CSRS + (size_t)E * 4;
constexpr size_t O_AH      = O_CSRD + (size_t)E * 4;
constexpr size_t O_Z       = O_AH + (size_t)N * D * 4;
constexpr size_t O_AZ1     = O_Z + (size_t)N * D * 4;
constexpr size_t O_AZ2     = O_AZ1 + (size_t)N * D * 4;
constexpr size_t O_FT      = O_AZ2 + (size_t)N * D * 4;   // 3 x [N,D] contiguous
constexpr size_t O_SCORE   = O_FT + 3 * (size_t)N * D * 4; // 3 x [E] f32, CSR-D order

// ---------------- kernels ----------------

// Per-edge: dedupe ownership via bitmap atomicOr, gather motif masks from
// dense A1/A2, count degrees for the two CSRs, flag motif endpoint nodes.
__global__ void edge_classify(const int* __restrict__ src, const int* __restrict__ dst,
                              const float* __restrict__ A1, const float* __restrict__ A2,
                              unsigned* __restrict__ bitmap,
                              int* __restrict__ srcCnt, int* __restrict__ dstCnt,
                              unsigned char* __restrict__ nf1, unsigned char* __restrict__ nf2,
                              unsigned char* __restrict__ eflags) {
    int i = blockIdx.x * blockDim.x + threadIdx.x;
    if (i >= E) return;
    int u = src[i], v = dst[i];
    long long key = ((long long)u << 13) | v;
    unsigned bit = 1u << (key & 31);
    unsigned old = atomicOr(&bitmap[key >> 5], bit);
    int own = ((old & bit) == 0) ? 1 : 0;
    float a1 = A1[key];
    float a2 = A2[key];
    int f1 = (a1 > 0.0f) ? 1 : 0;
    int f2 = (a2 > 0.0f) ? 1 : 0;
    eflags[i] = (unsigned char)(own | (f1 << 1) | (f2 << 2));
    if (own) atomicAdd(&srcCnt[u], 1);
    atomicAdd(&dstCnt[v], 1);
    if (f1) { nf1[u] = 1; nf1[v] = 1; }
    if (f2) { nf2[u] = 1; nf2[v] = 1; }
}

// Exclusive prefix scan of 8192 counts (one block per array).
__global__ void scan2(const int* __restrict__ srcCnt, int* __restrict__ srcPtr, int* __restrict__ srcFill,
                      const int* __restrict__ dstCnt, int* __restrict__ dstPtr, int* __restrict__ dstFill) {
    const int* cnt = (blockIdx.x == 0) ? srcCnt : dstCnt;
    int* ptr  = (blockIdx.x == 0) ? srcPtr : dstPtr;
    int* fill = (blockIdx.x == 0) ? srcFill : dstFill;
    __shared__ int ssum[256];
    int t = threadIdx.x;
    int base = t * 32;
    int loc[32];
    int s = 0;
    for (int j = 0; j < 32; ++j) { loc[j] = cnt[base + j]; s += loc[j]; }
    ssum[t] = s;
    __syncthreads();
    for (int off = 1; off < 256; off <<= 1) {
        int v = (t >= off) ? ssum[t - off] : 0;
        __syncthreads();
        ssum[t] += v;
        __syncthreads();
    }
    int ex = (t == 0) ? 0 : ssum[t - 1];
    for (int j = 0; j < 32; ++j) {
        ptr[base + j] = ex;
        fill[base + j] = ex;
        ex += loc[j];
    }
    if (t == 255) ptr[N] = ex;
}

// Scatter edges into src-CSR (owned only) and dst-CSR (all edges), flags packed.
__global__ void csr_fill(const int* __restrict__ src, const int* __restrict__ dst,
                         const unsigned char* __restrict__ eflags,
                         int* __restrict__ srcFill, int* __restrict__ dstFill,
                         int* __restrict__ csrS, int* __restrict__ csrD) {
    int i = blockIdx.x * blockDim.x + threadIdx.x;
    if (i >= E) return;
    int u = src[i], v = dst[i];
    int fl = eflags[i];
    int f12 = (fl >> 1) & 3;
    if (fl & 1) {
        int p = atomicAdd(&srcFill[u], 1);
        csrS[p] = v | (f12 << 13);
    }
    int p2 = atomicAdd(&dstFill[v], 1);
    csrD[p2] = u | (f12 << 13);
}

// Ah = A @ h over deduped edges. One wave per row, lane = feature.
__global__ void spmm_base(const int* __restrict__ srcPtr, const int* __restrict__ csrS,
                          const float* __restrict__ h, float* __restrict__ Ah) {
    int wid = threadIdx.x >> 6, lane = threadIdx.x & 63;
    int row = blockIdx.x * 4 + wid;
    if (row >= N) return;
    int b = srcPtr[row], e = srcPtr[row + 1];
    float acc = 0.0f;
    for (int j = b; j < e; ++j) {
        int v = csrS[j] & 8191;
        acc += h[(size_t)v * D + lane];
    }
    Ah[(size_t)row * D + lane] = acc;
}

// az1 = A1 @ Z, az2 = A2 @ Z in one pass (flags select contribution).
__global__ void spmm_motifs(const int* __restrict__ srcPtr, const int* __restrict__ csrS,
                            const float* __restrict__ Z,
                            float* __restrict__ az1, float* __restrict__ az2) {
    int wid = threadIdx.x >> 6, lane = threadIdx.x & 63;
    int row = blockIdx.x * 4 + wid;
    if (row >= N) return;
    int b = srcPtr[row], e = srcPtr[row + 1];
    float a1 = 0.0f, a2 = 0.0f;
    for (int j = b; j < e; ++j) {
        int ent = csrS[j];
        if ((ent >> 13) == 0) continue;
        float z = Z[(size_t)(ent & 8191) * D + lane];
        if (ent & (1 << 13)) a1 += z;
        if (ent & (1 << 14)) a2 += z;
    }
    az1[(size_t)row * D + lane] = a1;
    az2[(size_t)row * D + lane] = a2;
}

// Z[N,64] = X[N,64] @ W^T + bias. One wave per row via shfl broadcast.
__global__ void gemm64(const float* __restrict__ X, const float* __restrict__ W,
                       const float* __restrict__ bias, float* __restrict__ Y) {
    __shared__ float Wl[64 * 64];
    int t = threadIdx.x;
    for (int i = t; i < 4096; i += 256) {
        int r = i >> 6, c = i & 63;
        Wl[i] = W[c * 64 + r];                 // Wl[k][j] = W[j][k]
    }
    __syncthreads();
    int wid = t >> 6, lane = t & 63;
    int row = blockIdx.x * 4 + wid;
    float x = X[(size_t)row * D + lane];
    float acc = bias[lane];
    for (int k = 0; k < 64; ++k) {
        float bv = __shfl(x, k);
        acc = fmaf(bv, Wl[k * 64 + lane], acc);
    }
    Y[(size_t)row * D + lane] = acc;
}

// ftAll[m] = Xm @ fcm for the three motifs (blockIdx.y = motif).
__global__ void ft_gemm(const float* __restrict__ Z, const float* __restrict__ az1,
                        const float* __restrict__ az2,
                        const float* __restrict__ fc0, const float* __restrict__ fc1,
                        const float* __restrict__ fc2, float* __restrict__ ftAll) {
    int m = blockIdx.y;
    const float* X = (m == 0) ? Z : (m == 1) ? az1 : az2;
    const float* W = (m == 0) ? fc0 : (m == 1) ? fc1 : fc2;
    float* Y = ftAll + (size_t)m * N * D;
    __shared__ float Wl[64 * 64];
    int t = threadIdx.x;
    for (int i = t; i < 4096; i += 256) Wl[i] = W[i];   // Wl[k][j] = W[k][j]
    __syncthreads();
    int wid = t >> 6, lane = t & 63;
    int row = blockIdx.x * 4 + wid;
    float x = X[(size_t)row * D + lane];
    float acc = 0.0f;
    for (int k = 0; k < 64; ++k) {
        float bv = __shfl(x, k);
        acc = fmaf(bv, Wl[k * 64 + lane], acc);
    }
    Y[(size_t)row * D + lane] = acc;
}

// Per-edge attention scores for all 3 motifs, written in dst-CSR order.
// One wave per dst row v: ft[v] rows held in registers, one shfl-reduce per
// (edge, active motif). scoreAll[m*E + j] = <ft_m[u], ft_m[v]> / 8.
__global__ void edge_scores(const float* __restrict__ ftAll,
                            const int* __restrict__ dstPtr, const int* __restrict__ csrD,
                            float* __restrict__ scoreAll) {
    int t = threadIdx.x, wid = t >> 6, lane = t & 63;
    int row = blockIdx.x * 4 + wid;
    const float* ft0 = ftAll;
    const float* ft1 = ftAll + (size_t)N * D;
    const float* ft2 = ftAll + 2 * (size_t)N * D;
    float fv0 = ft0[(size_t)row * D + lane];
    float fv1 = ft1[(size_t)row * D + lane];
    float fv2 = ft2[(size_t)row * D + lane];
    int b = dstPtr[row], e = dstPtr[row + 1];
    for (int j = b; j < e; ++j) {
        int ent = csrD[j];
        size_t u = (size_t)(ent & 8191);
        float p0 = ft0[u * D + lane] * fv0;
        p0 += __shfl_xor(p0, 1);  p0 += __shfl_xor(p0, 2);  p0 += __shfl_xor(p0, 4);
        p0 += __shfl_xor(p0, 8);  p0 += __shfl_xor(p0, 16); p0 += __shfl_xor(p0, 32);
        if (lane == 0) scoreAll[j] = p0 * 0.125f;
        if (ent & (1 << 13)) {
            float p1 = ft1[u * D + lane] * fv1;
            p1 += __shfl_xor(p1, 1);  p1 += __shfl_xor(p1, 2);  p1 += __shfl_xor(p1, 4);
            p1 += __shfl_xor(p1, 8);  p1 += __shfl_xor(p1, 16); p1 += __shfl_xor(p1, 32);
            if (lane == 0) scoreAll[E + j] = p1 * 0.125f;
        }
        if (ent & (1 << 14)) {
            float p2 = ft2[u * D + lane] * fv2;
            p2 += __shfl_xor(p2, 1);  p2 += __shfl_xor(p2, 2);  p2 += __shfl_xor(p2, 4);
            p2 += __shfl_xor(p2, 8);  p2 += __shfl_xor(p2, 16); p2 += __shfl_xor(p2, 32);
            if (lane == 0) scoreAll[2 * E + j] = p2 * 0.125f;
        }
    }
}

// Fused edge-softmax + aggregate + pool, all 3 motifs (blockIdx.y = motif).
// Max pass lane-parallel over edges (coalesced score reads, ONE reduce/row);
// sum pass lane = feature with wave-uniform score/entry loads.
__global__ void gat_pool_multi(const float* __restrict__ ftAll,
                               const int* __restrict__ dstPtr, const int* __restrict__ csrD,
                               const float* __restrict__ scoreAll,
                               float* __restrict__ pooled) {
    int motif = blockIdx.y;
    const float* ft = ftAll + (size_t)motif * N * D;
    const float* sc = scoreAll + (size_t)motif * E;
    int t = threadIdx.x, wid = t >> 6, lane = t & 63;
    int row = blockIdx.x * 4 + wid;
    int b = dstPtr[row], e = dstPtr[row + 1];
    // max pass: lane = edge
    float m = -3.0e38f;
    for (int j = b + lane; j < e; j += 64) {
        int ent = csrD[j];
        bool act = (motif == 0) || ((ent >> (12 + motif)) & 1);
        if (act) m = fmaxf(m, sc[j]);
    }
    m = fmaxf(m, __shfl_xor(m, 1));  m = fmaxf(m, __shfl_xor(m, 2));
    m = fmaxf(m, __shfl_xor(m, 4));  m = fmaxf(m, __shfl_xor(m, 8));
    m = fmaxf(m, __shfl_xor(m, 16)); m = fmaxf(m, __shfl_xor(m, 32));
    // sum pass: lane = feature
    float den = 0.0f, acc = 0.0f;
    for (int j = b; j < e; ++j) {
        int ent = csrD[j];
        if (motif && !((ent >> (12 + motif)) & 1)) continue;
        float w = __expf(sc[j] - m);
        den += w;
        acc = fmaf(w, ft[(size_t)(ent & 8191) * D + lane], acc);
    }
    float pool = acc / fmaxf(den, 1e-9f);
    __shared__ float red[256];
    red[t] = pool;
    __syncthreads();
    if (wid == 0) {
        float s = red[lane] + red[64 + lane] + red[128 + lane] + red[192 + lane];
        atomicAdd(&pooled[motif * 64 + lane], s);
    }
}

// Final: motif node counts, divide pooled sums, 192x2 linear.
__global__ void final_kernel(const float* __restrict__ pooled,
                             const unsigned char* __restrict__ nf1, const unsigned char* __restrict__ nf2,
                             const float* __restrict__ lin_w, const float* __restrict__ lin_b,
                             float* __restrict__ out) {
    __shared__ int r1[256], r2[256];
    __shared__ float feat[192];
    __shared__ int cnt[2];
    int t = threadIdx.x;
    int s1 = 0, s2 = 0;
    for (int i = t; i < N; i += 256) { s1 += nf1[i]; s2 += nf2[i]; }
    r1[t] = s1; r2[t] = s2;
    __syncthreads();
    for (int off = 128; off > 0; off >>= 1) {
        if (t < off) { r1[t] += r1[t + off]; r2[t] += r2[t + off]; }
        __syncthreads();
    }
    if (t == 0) { cnt[0] = r1[0]; cnt[1] = r2[0]; }
    __syncthreads();
    if (t < 192) {
        int sel = t >> 6;
        float div = (sel == 0) ? (float)N : fmaxf((float)cnt[sel - 1], 1.0f);
        feat[t] = pooled[t] / div;
    }
    __syncthreads();
    if (t < 2) {
        float o = lin_b[t];
        for (int k = 0; k < 192; ++k) o = fmaf(feat[k], lin_w[k * 2 + t], o);
        out[t] = o;
    }
}

// ---------------- launch ----------------
extern "C" void kernel_launch(void* const* d_in, const int* in_sizes, int n_in,
                              void* d_out, int out_size, void* d_ws, size_t ws_size,
                              hipStream_t stream) {
    const float* h   = (const float*)d_in[0];
    // d_in[1] (dense A) is never needed: its structure == edge list, values == 1.
    const float* A1  = (const float*)d_in[2];
    const float* A2  = (const float*)d_in[3];
    const float* Ww  = (const float*)d_in[4];
    const float* Wb  = (const float*)d_in[5];
    const float* fc0 = (const float*)d_in[6];
    const float* fc1 = (const float*)d_in[7];
    const float* fc2 = (const float*)d_in[8];
    const float* lw  = (const float*)d_in[9];
    const float* lb  = (const float*)d_in[10];
    const int* src   = (const int*)d_in[11];
    const int* dst   = (const int*)d_in[12];
    float* out = (float*)d_out;

    char* w = (char*)d_ws;
    unsigned* bitmap   = (unsigned*)(w + O_BITMAP);
    int* srcCnt        = (int*)(w + O_SRCCNT);
    int* dstCnt        = (int*)(w + O_DSTCNT);
    unsigned char* nf1 = (unsigned char*)(w + O_NF1);
    unsigned char* nf2 = (unsigned char*)(w + O_NF2);
    float* pooled      = (float*)(w + O_POOLED);
    int* srcPtr        = (int*)(w + O_SRCPTR);
    int* dstPtr        = (int*)(w + O_DSTPTR);
    int* srcFill       = (int*)(w + O_SRCFILL);
    int* dstFill       = (int*)(w + O_DSTFILL);
    unsigned char* efl = (unsigned char*)(w + O_EFLAGS);
    int* csrS          = (int*)(w + O_CSRS);
    int* csrD          = (int*)(w + O_CSRD);
    float* Ah          = (float*)(w + O_AH);
    float* Z           = (float*)(w + O_Z);
    float* az1         = (float*)(w + O_AZ1);
    float* az2         = (float*)(w + O_AZ2);
    float* ftAll       = (float*)(w + O_FT);
    float* scoreAll    = (float*)(w + O_SCORE);

    hipMemsetAsync(w, 0, ZERO_END, stream);

    edge_classify<<<E / 256, 256, 0, stream>>>(src, dst, A1, A2, bitmap, srcCnt, dstCnt, nf1, nf2, efl);
    scan2<<<2, 256, 0, stream>>>(srcCnt, srcPtr, srcFill, dstCnt, dstPtr, dstFill);
    csr_fill<<<E / 256, 256, 0, stream>>>(src, dst, efl, srcFill, dstFill, csrS, csrD);

    spmm_base<<<N / 4, 256, 0, stream>>>(srcPtr, csrS, h, Ah);
    gemm64<<<N / 4, 256, 0, stream>>>(Ah, Ww, Wb, Z);             // Z = Ah @ Ww^T + Wb
    spmm_motifs<<<N / 4, 256, 0, stream>>>(srcPtr, csrS, Z, az1, az2);

    ft_gemm<<<dim3(N / 4, 3), 256, 0, stream>>>(Z, az1, az2, fc0, fc1, fc2, ftAll);
    edge_scores<<<N / 4, 256, 0, stream>>>(ftAll, dstPtr, csrD, scoreAll);
    gat_pool_multi<<<dim3(N / 4, 3), 256, 0, stream>>>(ftAll, dstPtr, csrD, scoreAll, pooled);

    final_kernel<<<1, 256, 0, stream>>>(pooled, nf1, nf2, lw, lb, out);
}

// Round 3
// 930.028 us; speedup vs baseline: 1.5030x; 1.0934x over previous
//
#include <hip/hip_runtime.h>

constexpr int N = 8192;
constexpr int D = 64;
constexpr int E = 524288;

// ---------------- workspace layout (bytes) ----------------
constexpr size_t SZ_BITMAP = (size_t)N * (size_t)N / 8;   // 8,388,608
constexpr size_t SZ_CNT    = 8256 * sizeof(int);          // >= (N+1)*4
constexpr size_t O_BITMAP  = 0;
constexpr size_t O_SRCCNT  = O_BITMAP + SZ_BITMAP;
constexpr size_t O_DSTCNT  = O_SRCCNT + SZ_CNT;
constexpr size_t O_NF1     = O_DSTCNT + SZ_CNT;
constexpr size_t O_NF2     = O_NF1 + N;
constexpr size_t O_POOLED  = O_NF2 + N;                   // 192 floats used
constexpr size_t ZERO_END  = O_POOLED + 1024;             // memset [0, ZERO_END)
constexpr size_t O_SRCPTR  = ZERO_END;
constexpr size_t O_DSTPTR  = O_SRCPTR + SZ_CNT;
constexpr size_t O_SRCFILL = O_DSTPTR + SZ_CNT;
constexpr size_t O_DSTFILL = O_SRCFILL + SZ_CNT;
constexpr size_t O_EFLAGS  = O_DSTFILL + SZ_CNT;          // E bytes
constexpr size_t O_CSRS    = O_EFLAGS + (size_t)E;
constexpr size_t O_CSRD    = O_CSRS + (size_t)E * 4;
constexpr size_t O_Z       = O_CSRD + (size_t)E * 4;
constexpr size_t O_FT      = O_Z + (size_t)N * D * 4;     // 3 x [N,D] contiguous

// ---------------- kernels ----------------

// Per-edge: dedupe ownership via bitmap atomicOr, gather motif masks from
// dense A1/A2, count degrees for the two CSRs, flag motif endpoint nodes.
__global__ void edge_classify(const int* __restrict__ src, const int* __restrict__ dst,
                              const float* __restrict__ A1, const float* __restrict__ A2,
                              unsigned* __restrict__ bitmap,
                              int* __restrict__ srcCnt, int* __restrict__ dstCnt,
                              unsigned char* __restrict__ nf1, unsigned char* __restrict__ nf2,
                              unsigned char* __restrict__ eflags) {
    int i = blockIdx.x * blockDim.x + threadIdx.x;
    if (i >= E) return;
    int u = src[i], v = dst[i];
    long long key = ((long long)u << 13) | v;
    unsigned bit = 1u << (key & 31);
    unsigned old = atomicOr(&bitmap[key >> 5], bit);
    int own = ((old & bit) == 0) ? 1 : 0;
    float a1 = A1[key];
    float a2 = A2[key];
    int f1 = (a1 > 0.0f) ? 1 : 0;
    int f2 = (a2 > 0.0f) ? 1 : 0;
    eflags[i] = (unsigned char)(own | (f1 << 1) | (f2 << 2));
    if (own) atomicAdd(&srcCnt[u], 1);
    atomicAdd(&dstCnt[v], 1);
    if (f1) { nf1[u] = 1; nf1[v] = 1; }
    if (f2) { nf2[u] = 1; nf2[v] = 1; }
}

// Exclusive prefix scan of 8192 counts (one block per array).
__global__ void scan2(const int* __restrict__ srcCnt, int* __restrict__ srcPtr, int* __restrict__ srcFill,
                      const int* __restrict__ dstCnt, int* __restrict__ dstPtr, int* __restrict__ dstFill) {
    const int* cnt = (blockIdx.x == 0) ? srcCnt : dstCnt;
    int* ptr  = (blockIdx.x == 0) ? srcPtr : dstPtr;
    int* fill = (blockIdx.x == 0) ? srcFill : dstFill;
    __shared__ int ssum[256];
    int t = threadIdx.x;
    int base = t * 32;
    int loc[32];
    int s = 0;
    for (int j = 0; j < 32; ++j) { loc[j] = cnt[base + j]; s += loc[j]; }
    ssum[t] = s;
    __syncthreads();
    for (int off = 1; off < 256; off <<= 1) {
        int v = (t >= off) ? ssum[t - off] : 0;
        __syncthreads();
        ssum[t] += v;
        __syncthreads();
    }
    int ex = (t == 0) ? 0 : ssum[t - 1];
    for (int j = 0; j < 32; ++j) {
        ptr[base + j] = ex;
        fill[base + j] = ex;
        ex += loc[j];
    }
    if (t == 255) ptr[N] = ex;
}

// Scatter edges into src-CSR (owned only) and dst-CSR (all edges), flags packed.
__global__ void csr_fill(const int* __restrict__ src, const int* __restrict__ dst,
                         const unsigned char* __restrict__ eflags,
                         int* __restrict__ srcFill, int* __restrict__ dstFill,
                         int* __restrict__ csrS, int* __restrict__ csrD) {
    int i = blockIdx.x * blockDim.x + threadIdx.x;
    if (i >= E) return;
    int u = src[i], v = dst[i];
    int fl = eflags[i];
    int f12 = (fl >> 1) & 3;
    if (fl & 1) {
        int p = atomicAdd(&srcFill[u], 1);
        csrS[p] = v | (f12 << 13);
    }
    int p2 = atomicAdd(&dstFill[v], 1);
    csrD[p2] = u | (f12 << 13);
}

// Row pipeline 1: Ah = A@h (dedup CSR gather) -> Z = Ah@Ww^T + Wb -> ft0 = Z@fc0.
// One wave per row, lane = feature; Ah/Z stay in registers.
__global__ void rowpipe1(const int* __restrict__ srcPtr, const int* __restrict__ csrS,
                         const float* __restrict__ h, const float* __restrict__ Ww,
                         const float* __restrict__ Wb, const float* __restrict__ fc0,
                         float* __restrict__ Z, float* __restrict__ ft0) {
    __shared__ float W1[64 * 64];   // W1[k][j] = Ww[j][k]
    __shared__ float W2[64 * 64];   // W2[k][j] = fc0[k][j]
    int t = threadIdx.x;
    for (int i = t; i < 4096; i += 256) {
        int r = i >> 6, c = i & 63;
        W1[i] = Ww[c * 64 + r];
        W2[i] = fc0[i];
    }
    __syncthreads();
    int wid = t >> 6, lane = t & 63;
    int row = blockIdx.x * 4 + wid;
    int b = srcPtr[row], e = srcPtr[row + 1];
    float ah = 0.0f;
    for (int j = b; j < e; ++j)
        ah += h[(size_t)(csrS[j] & 8191) * D + lane];
    float z = Wb[lane];
    #pragma unroll 8
    for (int k = 0; k < 64; ++k)
        z = fmaf(__shfl(ah, k), W1[k * 64 + lane], z);
    Z[(size_t)row * D + lane] = z;
    float f = 0.0f;
    #pragma unroll 8
    for (int k = 0; k < 64; ++k)
        f = fmaf(__shfl(z, k), W2[k * 64 + lane], f);
    ft0[(size_t)row * D + lane] = f;
}

// Row pipeline 2: az1 = A1@Z, az2 = A2@Z (flagged CSR gather, registers only)
// -> ft1 = az1@fc1, ft2 = az2@fc2.
__global__ void rowpipe2(const int* __restrict__ srcPtr, const int* __restrict__ csrS,
                         const float* __restrict__ Z,
                         const float* __restrict__ fc1, const float* __restrict__ fc2,
                         float* __restrict__ ft1, float* __restrict__ ft2) {
    __shared__ float W1[64 * 64];
    __shared__ float W2[64 * 64];
    int t = threadIdx.x;
    for (int i = t; i < 4096; i += 256) {
        W1[i] = fc1[i];
        W2[i] = fc2[i];
    }
    __syncthreads();
    int wid = t >> 6, lane = t & 63;
    int row = blockIdx.x * 4 + wid;
    int b = srcPtr[row], e = srcPtr[row + 1];
    float a1 = 0.0f, a2 = 0.0f;
    for (int j = b; j < e; ++j) {
        int ent = csrS[j];
        if ((ent >> 13) == 0) continue;
        float z = Z[(size_t)(ent & 8191) * D + lane];
        if (ent & (1 << 13)) a1 += z;
        if (ent & (1 << 14)) a2 += z;
    }
    float f1 = 0.0f, f2 = 0.0f;
    #pragma unroll 8
    for (int k = 0; k < 64; ++k) {
        f1 = fmaf(__shfl(a1, k), W1[k * 64 + lane], f1);
        f2 = fmaf(__shfl(a2, k), W2[k * 64 + lane], f2);
    }
    ft1[(size_t)row * D + lane] = f1;
    ft2[(size_t)row * D + lane] = f2;
}

// Fully fused per-motif GAT: SDDMM scores (lane = edge, float4 gathers vs
// LDS-broadcast ft[v]) + online softmax (ONE shfl-reduce pair per 64-edge
// chunk) + feature-parallel aggregation (weights/indices via LDS broadcast)
// + avg-pool accumulation. blockIdx.y = motif.
__global__ void gat_fused(const float* __restrict__ ftAll,
                          const int* __restrict__ dstPtr, const int* __restrict__ csrD,
                          float* __restrict__ pooled) {
    int motif = blockIdx.y;
    const float* ft = ftAll + (size_t)motif * N * D;
    int t = threadIdx.x, wid = t >> 6, lane = t & 63;
    int row = blockIdx.x * 4 + wid;
    __shared__ float fv[4][64];
    __shared__ float wbuf[4][64];
    __shared__ int ubuf[4][64];
    fv[wid][lane] = ft[(size_t)row * D + lane];
    int b = dstPtr[row], e = dstPtr[row + 1];
    float mrun = -3.0e38f, den = 0.0f, acc = 0.0f;
    for (int cb = b; cb < e; cb += 64) {
        int j = cb + lane;
        float s = -3.0e38f;
        int u = 0;
        bool act = false;
        if (j < e) {
            int ent = csrD[j];
            u = ent & 8191;
            act = (motif == 0) || ((ent >> (12 + motif)) & 1);
        }
        if (act) {
            const float* fu = ft + (size_t)u * D;
            float d0 = 0.0f, d1 = 0.0f;
            #pragma unroll
            for (int k = 0; k < 16; k += 2) {
                float4 a0 = *(const float4*)(fu + 4 * k);
                float4 b0 = *(const float4*)(&fv[wid][4 * k]);
                float4 a1 = *(const float4*)(fu + 4 * k + 4);
                float4 b1 = *(const float4*)(&fv[wid][4 * k + 4]);
                d0 = fmaf(a0.x, b0.x, d0); d0 = fmaf(a0.y, b0.y, d0);
                d0 = fmaf(a0.z, b0.z, d0); d0 = fmaf(a0.w, b0.w, d0);
                d1 = fmaf(a1.x, b1.x, d1); d1 = fmaf(a1.y, b1.y, d1);
                d1 = fmaf(a1.z, b1.z, d1); d1 = fmaf(a1.w, b1.w, d1);
            }
            s = (d0 + d1) * 0.125f;
        }
        // chunk max (one 6-shfl chain per chunk)
        float cm = s;
        cm = fmaxf(cm, __shfl_xor(cm, 1));  cm = fmaxf(cm, __shfl_xor(cm, 2));
        cm = fmaxf(cm, __shfl_xor(cm, 4));  cm = fmaxf(cm, __shfl_xor(cm, 8));
        cm = fmaxf(cm, __shfl_xor(cm, 16)); cm = fmaxf(cm, __shfl_xor(cm, 32));
        float newm = fmaxf(mrun, cm);
        float scale = __expf(mrun - newm);        // 1.0 when both -3e38
        float wj = act ? __expf(s - newm) : 0.0f;
        wbuf[wid][lane] = wj;
        ubuf[wid][lane] = u;
        float cs = wj;
        cs += __shfl_xor(cs, 1);  cs += __shfl_xor(cs, 2);  cs += __shfl_xor(cs, 4);
        cs += __shfl_xor(cs, 8);  cs += __shfl_xor(cs, 16); cs += __shfl_xor(cs, 32);
        den = den * scale + cs;
        acc *= scale;
        int csize = min(64, e - cb);
        for (int q = 0; q < csize; ++q) {
            float wq = wbuf[wid][q];
            if (wq > 0.0f)
                acc = fmaf(wq, ft[(size_t)ubuf[wid][q] * D + lane], acc);
        }
        mrun = newm;
    }
    float pool = acc / fmaxf(den, 1e-9f);
    __shared__ float red[256];
    red[t] = pool;
    __syncthreads();
    if (wid == 0) {
        float s = red[lane] + red[64 + lane] + red[128 + lane] + red[192 + lane];
        atomicAdd(&pooled[motif * 64 + lane], s);
    }
}

// Final: motif node counts, divide pooled sums, 192x2 linear.
__global__ void final_kernel(const float* __restrict__ pooled,
                             const unsigned char* __restrict__ nf1, const unsigned char* __restrict__ nf2,
                             const float* __restrict__ lin_w, const float* __restrict__ lin_b,
                             float* __restrict__ out) {
    __shared__ int r1[256], r2[256];
    __shared__ float feat[192];
    __shared__ int cnt[2];
    int t = threadIdx.x;
    int s1 = 0, s2 = 0;
    for (int i = t; i < N; i += 256) { s1 += nf1[i]; s2 += nf2[i]; }
    r1[t] = s1; r2[t] = s2;
    __syncthreads();
    for (int off = 128; off > 0; off >>= 1) {
        if (t < off) { r1[t] += r1[t + off]; r2[t] += r2[t + off]; }
        __syncthreads();
    }
    if (t == 0) { cnt[0] = r1[0]; cnt[1] = r2[0]; }
    __syncthreads();
    if (t < 192) {
        int sel = t >> 6;
        float div = (sel == 0) ? (float)N : fmaxf((float)cnt[sel - 1], 1.0f);
        feat[t] = pooled[t] / div;
    }
    __syncthreads();
    if (t < 2) {
        float o = lin_b[t];
        for (int k = 0; k < 192; ++k) o = fmaf(feat[k], lin_w[k * 2 + t], o);
        out[t] = o;
    }
}

// ---------------- launch ----------------
extern "C" void kernel_launch(void* const* d_in, const int* in_sizes, int n_in,
                              void* d_out, int out_size, void* d_ws, size_t ws_size,
                              hipStream_t stream) {
    const float* h   = (const float*)d_in[0];
    // d_in[1] (dense A) never read: structure == edge list, values == 1.
    const float* A1  = (const float*)d_in[2];
    const float* A2  = (const float*)d_in[3];
    const float* Ww  = (const float*)d_in[4];
    const float* Wb  = (const float*)d_in[5];
    const float* fc0 = (const float*)d_in[6];
    const float* fc1 = (const float*)d_in[7];
    const float* fc2 = (const float*)d_in[8];
    const float* lw  = (const float*)d_in[9];
    const float* lb  = (const float*)d_in[10];
    const int* src   = (const int*)d_in[11];
    const int* dst   = (const int*)d_in[12];
    float* out = (float*)d_out;

    char* w = (char*)d_ws;
    unsigned* bitmap   = (unsigned*)(w + O_BITMAP);
    int* srcCnt        = (int*)(w + O_SRCCNT);
    int* dstCnt        = (int*)(w + O_DSTCNT);
    unsigned char* nf1 = (unsigned char*)(w + O_NF1);
    unsigned char* nf2 = (unsigned char*)(w + O_NF2);
    float* pooled      = (float*)(w + O_POOLED);
    int* srcPtr        = (int*)(w + O_SRCPTR);
    int* dstPtr        = (int*)(w + O_DSTPTR);
    int* srcFill       = (int*)(w + O_SRCFILL);
    int* dstFill       = (int*)(w + O_DSTFILL);
    unsigned char* efl = (unsigned char*)(w + O_EFLAGS);
    int* csrS          = (int*)(w + O_CSRS);
    int* csrD          = (int*)(w + O_CSRD);
    float* Z           = (float*)(w + O_Z);
    float* ftAll       = (float*)(w + O_FT);
    float* ft1         = ftAll + (size_t)N * D;
    float* ft2         = ftAll + 2 * (size_t)N * D;

    hipMemsetAsync(w, 0, ZERO_END, stream);

    edge_classify<<<E / 256, 256, 0, stream>>>(src, dst, A1, A2, bitmap, srcCnt, dstCnt, nf1, nf2, efl);
    scan2<<<2, 256, 0, stream>>>(srcCnt, srcPtr, srcFill, dstCnt, dstPtr, dstFill);
    csr_fill<<<E / 256, 256, 0, stream>>>(src, dst, efl, srcFill, dstFill, csrS, csrD);

    rowpipe1<<<N / 4, 256, 0, stream>>>(srcPtr, csrS, h, Ww, Wb, fc0, Z, ftAll);
    rowpipe2<<<N / 4, 256, 0, stream>>>(srcPtr, csrS, Z, fc1, fc2, ft1, ft2);

    gat_fused<<<dim3(N / 4, 3), 256, 0, stream>>>(ftAll, dstPtr, csrD, pooled);

    final_kernel<<<1, 256, 0, stream>>>(pooled, nf1, nf2, lw, lb, out);
}

// Round 4
// 842.693 us; speedup vs baseline: 1.6588x; 1.1036x over previous
//
#include <hip/hip_runtime.h>

constexpr int N = 8192;
constexpr int D = 64;
constexpr int E = 524288;
constexpr int ND = N * D;

// ---------------- workspace layout (bytes) ----------------
constexpr size_t SZ_BITMAP = (size_t)N * (size_t)N / 8;   // 8,388,608
constexpr size_t SZ_CNT    = 8256 * sizeof(int);          // >= (N+1)*4
constexpr size_t O_BITMAP  = 0;
constexpr size_t O_SRCCNT  = O_BITMAP + SZ_BITMAP;
constexpr size_t O_DSTCNT  = O_SRCCNT + SZ_CNT;
constexpr size_t O_NF1     = O_DSTCNT + SZ_CNT;
constexpr size_t O_NF2     = O_NF1 + N;
constexpr size_t O_POOLED  = O_NF2 + N;                   // 192 floats used
constexpr size_t ZERO_END  = O_POOLED + 1024;             // memset [0, ZERO_END)
constexpr size_t O_SRCPTR  = ZERO_END;
constexpr size_t O_DSTPTR  = O_SRCPTR + SZ_CNT;
constexpr size_t O_SRCFILL = O_DSTPTR + SZ_CNT;
constexpr size_t O_DSTFILL = O_SRCFILL + SZ_CNT;
constexpr size_t O_EFLAGS  = O_DSTFILL + SZ_CNT;          // E bytes
constexpr size_t O_CSRS    = O_EFLAGS + (size_t)E;
constexpr size_t O_CSRD    = O_CSRS + (size_t)E * 4;
constexpr size_t O_Z       = O_CSRD + (size_t)E * 4;
constexpr size_t O_FT      = O_Z + (size_t)N * D * 4;     // 3 x [N,D] contiguous

// ---------------- kernels ----------------

// Per-edge: dedupe ownership via bitmap atomicOr, gather motif masks from
// dense A1/A2, count degrees for the two CSRs, flag motif endpoint nodes.
__global__ void __launch_bounds__(256) edge_classify(
        const int* __restrict__ src, const int* __restrict__ dst,
        const float* __restrict__ A1, const float* __restrict__ A2,
        unsigned* __restrict__ bitmap,
        int* __restrict__ srcCnt, int* __restrict__ dstCnt,
        unsigned char* __restrict__ nf1, unsigned char* __restrict__ nf2,
        unsigned char* __restrict__ eflags) {
    int i = blockIdx.x * blockDim.x + threadIdx.x;
    if (i >= E) return;
    int u = src[i], v = dst[i];
    long long key = ((long long)u << 13) | v;
    unsigned bit = 1u << (key & 31);
    unsigned old = atomicOr(&bitmap[key >> 5], bit);
    int own = ((old & bit) == 0) ? 1 : 0;
    float a1 = A1[key];
    float a2 = A2[key];
    int f1 = (a1 > 0.0f) ? 1 : 0;
    int f2 = (a2 > 0.0f) ? 1 : 0;
    eflags[i] = (unsigned char)(own | (f1 << 1) | (f2 << 2));
    if (own) atomicAdd(&srcCnt[u], 1);
    atomicAdd(&dstCnt[v], 1);
    if (f1) { nf1[u] = 1; nf1[v] = 1; }
    if (f2) { nf2[u] = 1; nf2[v] = 1; }
}

// Exclusive prefix scan of 8192 counts (one block per array).
__global__ void __launch_bounds__(256) scan2(
        const int* __restrict__ srcCnt, int* __restrict__ srcPtr, int* __restrict__ srcFill,
        const int* __restrict__ dstCnt, int* __restrict__ dstPtr, int* __restrict__ dstFill) {
    const int* cnt = (blockIdx.x == 0) ? srcCnt : dstCnt;
    int* ptr  = (blockIdx.x == 0) ? srcPtr : dstPtr;
    int* fill = (blockIdx.x == 0) ? srcFill : dstFill;
    __shared__ int ssum[256];
    int t = threadIdx.x;
    int base = t * 32;
    int loc[32];
    int s = 0;
    for (int j = 0; j < 32; ++j) { loc[j] = cnt[base + j]; s += loc[j]; }
    ssum[t] = s;
    __syncthreads();
    for (int off = 1; off < 256; off <<= 1) {
        int v = (t >= off) ? ssum[t - off] : 0;
        __syncthreads();
        ssum[t] += v;
        __syncthreads();
    }
    int ex = (t == 0) ? 0 : ssum[t - 1];
    for (int j = 0; j < 32; ++j) {
        ptr[base + j] = ex;
        fill[base + j] = ex;
        ex += loc[j];
    }
    if (t == 255) ptr[N] = ex;
}

// Scatter edges into src-CSR (owned only) and dst-CSR (all edges), flags packed.
__global__ void __launch_bounds__(256) csr_fill(
        const int* __restrict__ src, const int* __restrict__ dst,
        const unsigned char* __restrict__ eflags,
        int* __restrict__ srcFill, int* __restrict__ dstFill,
        int* __restrict__ csrS, int* __restrict__ csrD) {
    int i = blockIdx.x * blockDim.x + threadIdx.x;
    if (i >= E) return;
    int u = src[i], v = dst[i];
    int fl = eflags[i];
    int f12 = (fl >> 1) & 3;
    if (fl & 1) {
        int p = atomicAdd(&srcFill[u], 1);
        csrS[p] = v | (f12 << 13);
    }
    int p2 = atomicAdd(&dstFill[v], 1);
    csrD[p2] = u | (f12 << 13);
}

// Row pipeline 1: Ah = A@h (dedup CSR gather, 4-way ILP) -> Z = Ah@Ww^T + Wb
// -> ft0 = Z@fc0. One wave per row, lane = feature; Ah/Z stay in registers.
__global__ void __launch_bounds__(256) rowpipe1(
        const int* __restrict__ srcPtr, const int* __restrict__ csrS,
        const float* __restrict__ h, const float* __restrict__ Ww,
        const float* __restrict__ Wb, const float* __restrict__ fc0,
        float* __restrict__ Z, float* __restrict__ ft0) {
    __shared__ float W1[64 * 64];   // W1[k][j] = Ww[j][k]
    __shared__ float W2[64 * 64];   // W2[k][j] = fc0[k][j]
    int t = threadIdx.x;
    for (int i = t; i < 4096; i += 256) {
        int r = i >> 6, c = i & 63;
        W1[i] = Ww[c * 64 + r];
        W2[i] = fc0[i];
    }
    __syncthreads();
    int wid = t >> 6, lane = t & 63;
    int row = blockIdx.x * 4 + wid;
    int b = srcPtr[row], e = srcPtr[row + 1];
    float a0 = 0.0f, a1 = 0.0f, a2 = 0.0f, a3 = 0.0f;
    int j = b;
    for (; j + 3 < e; j += 4) {
        int u0 = csrS[j] & 8191, u1 = csrS[j + 1] & 8191;
        int u2 = csrS[j + 2] & 8191, u3 = csrS[j + 3] & 8191;
        a0 += h[(size_t)u0 * D + lane];
        a1 += h[(size_t)u1 * D + lane];
        a2 += h[(size_t)u2 * D + lane];
        a3 += h[(size_t)u3 * D + lane];
    }
    for (; j < e; ++j) a0 += h[(size_t)(csrS[j] & 8191) * D + lane];
    float ah = (a0 + a1) + (a2 + a3);
    float z = Wb[lane];
    #pragma unroll 8
    for (int k = 0; k < 64; ++k)
        z = fmaf(__shfl(ah, k), W1[k * 64 + lane], z);
    Z[(size_t)row * D + lane] = z;
    float f = 0.0f;
    #pragma unroll 8
    for (int k = 0; k < 64; ++k)
        f = fmaf(__shfl(z, k), W2[k * 64 + lane], f);
    ft0[(size_t)row * D + lane] = f;
}

// Row pipeline 2: az1 = A1@Z, az2 = A2@Z (flagged CSR gather, 2-way ILP)
// -> ft1 = az1@fc1, ft2 = az2@fc2.
__global__ void __launch_bounds__(256) rowpipe2(
        const int* __restrict__ srcPtr, const int* __restrict__ csrS,
        const float* __restrict__ Z,
        const float* __restrict__ fc1, const float* __restrict__ fc2,
        float* __restrict__ ft1, float* __restrict__ ft2) {
    __shared__ float W1[64 * 64];
    __shared__ float W2[64 * 64];
    int t = threadIdx.x;
    for (int i = t; i < 4096; i += 256) {
        W1[i] = fc1[i];
        W2[i] = fc2[i];
    }
    __syncthreads();
    int wid = t >> 6, lane = t & 63;
    int row = blockIdx.x * 4 + wid;
    int b = srcPtr[row], e = srcPtr[row + 1];
    float a1x = 0.0f, a2x = 0.0f, a1y = 0.0f, a2y = 0.0f;
    int j = b;
    for (; j + 1 < e; j += 2) {
        int e0 = csrS[j], e1 = csrS[j + 1];
        if (e0 >> 13) {
            float z = Z[(size_t)(e0 & 8191) * D + lane];
            if (e0 & (1 << 13)) a1x += z;
            if (e0 & (1 << 14)) a2x += z;
        }
        if (e1 >> 13) {
            float z = Z[(size_t)(e1 & 8191) * D + lane];
            if (e1 & (1 << 13)) a1y += z;
            if (e1 & (1 << 14)) a2y += z;
        }
    }
    for (; j < e; ++j) {
        int e0 = csrS[j];
        if (e0 >> 13) {
            float z = Z[(size_t)(e0 & 8191) * D + lane];
            if (e0 & (1 << 13)) a1x += z;
            if (e0 & (1 << 14)) a2x += z;
        }
    }
    float s1 = a1x + a1y, s2 = a2x + a2y;
    float f1 = 0.0f, f2 = 0.0f;
    #pragma unroll 8
    for (int k = 0; k < 64; ++k) {
        f1 = fmaf(__shfl(s1, k), W1[k * 64 + lane], f1);
        f2 = fmaf(__shfl(s2, k), W2[k * 64 + lane], f2);
    }
    ft1[(size_t)row * D + lane] = f1;
    ft2[(size_t)row * D + lane] = f2;
}

// Fully fused GAT, ALL 3 motifs in ONE dst-CSR walk. Per 64-edge chunk:
// lane = edge SDDMM (conditional per motif), 3 interleaved shfl reduce chains,
// weights packed float4 in LDS, then lane = feature aggregation with 2-way
// unrolled independent accumulators. Online-softmax rescale across chunks.
__global__ void __launch_bounds__(256) gat_fused_all(
        const float* __restrict__ ftAll, const int* __restrict__ dstPtr,
        const int* __restrict__ csrD, float* __restrict__ pooled) {
    int t = threadIdx.x, wid = t >> 6, lane = t & 63;
    int row = blockIdx.x * 4 + wid;
    __shared__ float fv[4][3][64];
    __shared__ float4 sw[4][64];
    __shared__ float red[3][256];
    const float* ft0 = ftAll;
    fv[wid][0][lane] = ft0[(size_t)row * D + lane];
    fv[wid][1][lane] = ft0[ND + (size_t)row * D + lane];
    fv[wid][2][lane] = ft0[2 * ND + (size_t)row * D + lane];
    const float4* fq0 = (const float4*)fv[wid][0];
    const float4* fq1 = (const float4*)fv[wid][1];
    const float4* fq2 = (const float4*)fv[wid][2];
    int b = dstPtr[row], e = dstPtr[row + 1];
    float mr0 = -3.0e38f, mr1 = -3.0e38f, mr2 = -3.0e38f;
    float den0 = 0.0f, den1 = 0.0f, den2 = 0.0f;
    float a0x = 0.0f, a0y = 0.0f, a1x = 0.0f, a1y = 0.0f, a2x = 0.0f, a2y = 0.0f;
    for (int cb = b; cb < e; cb += 64) {
        int j = cb + lane;
        bool valid = j < e;
        int ent = valid ? csrD[j] : 0;
        int u = ent & 8191;
        bool act1 = valid && (ent & (1 << 13));
        bool act2 = valid && (ent & (1 << 14));
        float s0 = -3.0e38f, s1 = -3.0e38f, s2 = -3.0e38f;
        const float4* pu = (const float4*)(ft0 + (size_t)u * D);
        if (valid) {
            float d0 = 0.0f, d1 = 0.0f;
            #pragma unroll
            for (int k = 0; k < 16; k += 2) {
                float4 a = pu[k], bq = fq0[k];
                float4 c = pu[k + 1], dq = fq0[k + 1];
                d0 = fmaf(a.x, bq.x, d0); d0 = fmaf(a.y, bq.y, d0);
                d0 = fmaf(a.z, bq.z, d0); d0 = fmaf(a.w, bq.w, d0);
                d1 = fmaf(c.x, dq.x, d1); d1 = fmaf(c.y, dq.y, d1);
                d1 = fmaf(c.z, dq.z, d1); d1 = fmaf(c.w, dq.w, d1);
            }
            s0 = (d0 + d1) * 0.125f;
        }
        if (act1) {
            const float4* p1 = pu + ND / 4;
            float d0 = 0.0f, d1 = 0.0f;
            #pragma unroll
            for (int k = 0; k < 16; k += 2) {
                float4 a = p1[k], bq = fq1[k];
                float4 c = p1[k + 1], dq = fq1[k + 1];
                d0 = fmaf(a.x, bq.x, d0); d0 = fmaf(a.y, bq.y, d0);
                d0 = fmaf(a.z, bq.z, d0); d0 = fmaf(a.w, bq.w, d0);
                d1 = fmaf(c.x, dq.x, d1); d1 = fmaf(c.y, dq.y, d1);
                d1 = fmaf(c.z, dq.z, d1); d1 = fmaf(c.w, dq.w, d1);
            }
            s1 = (d0 + d1) * 0.125f;
        }
        if (act2) {
            const float4* p2 = pu + 2 * (ND / 4);
            float d0 = 0.0f, d1 = 0.0f;
            #pragma unroll
            for (int k = 0; k < 16; k += 2) {
                float4 a = p2[k], bq = fq2[k];
                float4 c = p2[k + 1], dq = fq2[k + 1];
                d0 = fmaf(a.x, bq.x, d0); d0 = fmaf(a.y, bq.y, d0);
                d0 = fmaf(a.z, bq.z, d0); d0 = fmaf(a.w, bq.w, d0);
                d1 = fmaf(c.x, dq.x, d1); d1 = fmaf(c.y, dq.y, d1);
                d1 = fmaf(c.z, dq.z, d1); d1 = fmaf(c.w, dq.w, d1);
            }
            s2 = (d0 + d1) * 0.125f;
        }
        // three interleaved max-reduce chains (independent -> ILP)
        float c0 = s0, c1 = s1, c2 = s2;
        c0 = fmaxf(c0, __shfl_xor(c0, 1));  c1 = fmaxf(c1, __shfl_xor(c1, 1));  c2 = fmaxf(c2, __shfl_xor(c2, 1));
        c0 = fmaxf(c0, __shfl_xor(c0, 2));  c1 = fmaxf(c1, __shfl_xor(c1, 2));  c2 = fmaxf(c2, __shfl_xor(c2, 2));
        c0 = fmaxf(c0, __shfl_xor(c0, 4));  c1 = fmaxf(c1, __shfl_xor(c1, 4));  c2 = fmaxf(c2, __shfl_xor(c2, 4));
        c0 = fmaxf(c0, __shfl_xor(c0, 8));  c1 = fmaxf(c1, __shfl_xor(c1, 8));  c2 = fmaxf(c2, __shfl_xor(c2, 8));
        c0 = fmaxf(c0, __shfl_xor(c0, 16)); c1 = fmaxf(c1, __shfl_xor(c1, 16)); c2 = fmaxf(c2, __shfl_xor(c2, 16));
        c0 = fmaxf(c0, __shfl_xor(c0, 32)); c1 = fmaxf(c1, __shfl_xor(c1, 32)); c2 = fmaxf(c2, __shfl_xor(c2, 32));
        float nm0 = fmaxf(mr0, c0), nm1 = fmaxf(mr1, c1), nm2 = fmaxf(mr2, c2);
        float sc0 = __expf(mr0 - nm0), sc1 = __expf(mr1 - nm1), sc2 = __expf(mr2 - nm2);
        float w0 = valid ? __expf(s0 - nm0) : 0.0f;
        float w1 = act1 ? __expf(s1 - nm1) : 0.0f;
        float w2 = act2 ? __expf(s2 - nm2) : 0.0f;
        sw[wid][lane] = make_float4(w0, w1, w2, __int_as_float(u));
        float t0 = w0, t1 = w1, t2 = w2;
        t0 += __shfl_xor(t0, 1);  t1 += __shfl_xor(t1, 1);  t2 += __shfl_xor(t2, 1);
        t0 += __shfl_xor(t0, 2);  t1 += __shfl_xor(t1, 2);  t2 += __shfl_xor(t2, 2);
        t0 += __shfl_xor(t0, 4);  t1 += __shfl_xor(t1, 4);  t2 += __shfl_xor(t2, 4);
        t0 += __shfl_xor(t0, 8);  t1 += __shfl_xor(t1, 8);  t2 += __shfl_xor(t2, 8);
        t0 += __shfl_xor(t0, 16); t1 += __shfl_xor(t1, 16); t2 += __shfl_xor(t2, 16);
        t0 += __shfl_xor(t0, 32); t1 += __shfl_xor(t1, 32); t2 += __shfl_xor(t2, 32);
        den0 = den0 * sc0 + t0; den1 = den1 * sc1 + t1; den2 = den2 * sc2 + t2;
        a0x *= sc0; a0y *= sc0; a1x *= sc1; a1y *= sc1; a2x *= sc2; a2y *= sc2;
        mr0 = nm0; mr1 = nm1; mr2 = nm2;
        // aggregation: lane = feature, 2-way unrolled independent accumulators
        int csize = min(64, e - cb);
        const float* fbase = ft0 + lane;
        int q = 0;
        for (; q + 1 < csize; q += 2) {
            float4 e0 = sw[wid][q], e1 = sw[wid][q + 1];
            const float* p0 = fbase + (size_t)__float_as_int(e0.w) * D;
            const float* p1 = fbase + (size_t)__float_as_int(e1.w) * D;
            a0x = fmaf(e0.x, p0[0], a0x);
            a0y = fmaf(e1.x, p1[0], a0y);
            if (e0.y > 0.0f) a1x = fmaf(e0.y, p0[ND], a1x);
            if (e1.y > 0.0f) a1y = fmaf(e1.y, p1[ND], a1y);
            if (e0.z > 0.0f) a2x = fmaf(e0.z, p0[2 * ND], a2x);
            if (e1.z > 0.0f) a2y = fmaf(e1.z, p1[2 * ND], a2y);
        }
        if (q < csize) {
            float4 e0 = sw[wid][q];
            const float* p0 = fbase + (size_t)__float_as_int(e0.w) * D;
            a0x = fmaf(e0.x, p0[0], a0x);
            if (e0.y > 0.0f) a1x = fmaf(e0.y, p0[ND], a1x);
            if (e0.z > 0.0f) a2x = fmaf(e0.z, p0[2 * ND], a2x);
        }
    }
    red[0][t] = (a0x + a0y) / fmaxf(den0, 1e-9f);
    red[1][t] = (a1x + a1y) / fmaxf(den1, 1e-9f);
    red[2][t] = (a2x + a2y) / fmaxf(den2, 1e-9f);
    __syncthreads();
    if (wid < 3) {
        float s = red[wid][lane] + red[wid][64 + lane] + red[wid][128 + lane] + red[wid][192 + lane];
        atomicAdd(&pooled[wid * 64 + lane], s);
    }
}

// Final: motif node counts, divide pooled sums, 192x2 linear.
__global__ void __launch_bounds__(256) final_kernel(
        const float* __restrict__ pooled,
        const unsigned char* __restrict__ nf1, const unsigned char* __restrict__ nf2,
        const float* __restrict__ lin_w, const float* __restrict__ lin_b,
        float* __restrict__ out) {
    __shared__ int r1[256], r2[256];
    __shared__ float feat[192];
    __shared__ int cnt[2];
    int t = threadIdx.x;
    int s1 = 0, s2 = 0;
    for (int i = t; i < N; i += 256) { s1 += nf1[i]; s2 += nf2[i]; }
    r1[t] = s1; r2[t] = s2;
    __syncthreads();
    for (int off = 128; off > 0; off >>= 1) {
        if (t < off) { r1[t] += r1[t + off]; r2[t] += r2[t + off]; }
        __syncthreads();
    }
    if (t == 0) { cnt[0] = r1[0]; cnt[1] = r2[0]; }
    __syncthreads();
    if (t < 192) {
        int sel = t >> 6;
        float div = (sel == 0) ? (float)N : fmaxf((float)cnt[sel - 1], 1.0f);
        feat[t] = pooled[t] / div;
    }
    __syncthreads();
    if (t < 2) {
        float o = lin_b[t];
        for (int k = 0; k < 192; ++k) o = fmaf(feat[k], lin_w[k * 2 + t], o);
        out[t] = o;
    }
}

// ---------------- launch ----------------
extern "C" void kernel_launch(void* const* d_in, const int* in_sizes, int n_in,
                              void* d_out, int out_size, void* d_ws, size_t ws_size,
                              hipStream_t stream) {
    const float* h   = (const float*)d_in[0];
    // d_in[1] (dense A) never read: structure == edge list, values == 1.
    const float* A1  = (const float*)d_in[2];
    const float* A2  = (const float*)d_in[3];
    const float* Ww  = (const float*)d_in[4];
    const float* Wb  = (const float*)d_in[5];
    const float* fc0 = (const float*)d_in[6];
    const float* fc1 = (const float*)d_in[7];
    const float* fc2 = (const float*)d_in[8];
    const float* lw  = (const float*)d_in[9];
    const float* lb  = (const float*)d_in[10];
    const int* src   = (const int*)d_in[11];
    const int* dst   = (const int*)d_in[12];
    float* out = (float*)d_out;

    char* w = (char*)d_ws;
    unsigned* bitmap   = (unsigned*)(w + O_BITMAP);
    int* srcCnt        = (int*)(w + O_SRCCNT);
    int* dstCnt        = (int*)(w + O_DSTCNT);
    unsigned char* nf1 = (unsigned char*)(w + O_NF1);
    unsigned char* nf2 = (unsigned char*)(w + O_NF2);
    float* pooled      = (float*)(w + O_POOLED);
    int* srcPtr        = (int*)(w + O_SRCPTR);
    int* dstPtr        = (int*)(w + O_DSTPTR);
    int* srcFill       = (int*)(w + O_SRCFILL);
    int* dstFill       = (int*)(w + O_DSTFILL);
    unsigned char* efl = (unsigned char*)(w + O_EFLAGS);
    int* csrS          = (int*)(w + O_CSRS);
    int* csrD          = (int*)(w + O_CSRD);
    float* Z           = (float*)(w + O_Z);
    float* ftAll       = (float*)(w + O_FT);
    float* ft1         = ftAll + (size_t)ND;
    float* ft2         = ftAll + 2 * (size_t)ND;

    hipMemsetAsync(w, 0, ZERO_END, stream);

    edge_classify<<<E / 256, 256, 0, stream>>>(src, dst, A1, A2, bitmap, srcCnt, dstCnt, nf1, nf2, efl);
    scan2<<<2, 256, 0, stream>>>(srcCnt, srcPtr, srcFill, dstCnt, dstPtr, dstFill);
    csr_fill<<<E / 256, 256, 0, stream>>>(src, dst, efl, srcFill, dstFill, csrS, csrD);

    rowpipe1<<<N / 4, 256, 0, stream>>>(srcPtr, csrS, h, Ww, Wb, fc0, Z, ftAll);
    rowpipe2<<<N / 4, 256, 0, stream>>>(srcPtr, csrS, Z, fc1, fc2, ft1, ft2);

    gat_fused_all<<<N / 4, 256, 0, stream>>>(ftAll, dstPtr, csrD, pooled);

    final_kernel<<<1, 256, 0, stream>>>(pooled, nf1, nf2, lw, lb, out);
}

// Round 7
// 832.141 us; speedup vs baseline: 1.6798x; 1.0127x over previous
//
#include <hip/hip_runtime.h>

constexpr int N = 8192;
constexpr int D = 64;
constexpr int E = 524288;
constexpr int ND = N * D;

// ---------------- workspace layout (bytes) ----------------
constexpr size_t SZ_BITMAP = (size_t)N * (size_t)N / 8;   // 8,388,608
constexpr size_t SZ_CNT    = 8256 * sizeof(int);          // >= (N+1)*4
constexpr size_t O_BITMAP  = 0;
constexpr size_t O_SRCCNT  = O_BITMAP + SZ_BITMAP;
constexpr size_t O_DSTCNT  = O_SRCCNT + SZ_CNT;
constexpr size_t O_NF1     = O_DSTCNT + SZ_CNT;
constexpr size_t O_NF2     = O_NF1 + N;
constexpr size_t O_POOLED  = O_NF2 + N;                   // 192 floats used
constexpr size_t O_BETA    = O_POOLED + 1024;             // 3 x N floats
constexpr size_t ZERO_END  = O_BETA + 3 * (size_t)N * 4;  // memset [0, ZERO_END)
constexpr size_t O_SRCPTR  = ZERO_END;
constexpr size_t O_DSTPTR  = O_SRCPTR + SZ_CNT;
constexpr size_t O_SRCFILL = O_DSTPTR + SZ_CNT;
constexpr size_t O_DSTFILL = O_SRCFILL + SZ_CNT;
constexpr size_t O_EFLAGS  = O_DSTFILL + SZ_CNT;          // E bytes
constexpr size_t O_CSRS    = O_EFLAGS + (size_t)E;
constexpr size_t O_CSRD    = O_CSRS + (size_t)E * 4;
constexpr size_t O_Z       = O_CSRD + (size_t)E * 4;
constexpr size_t O_FT      = O_Z + (size_t)N * D * 4;     // 3 x [N,D] contiguous

// ---------------- kernels ----------------

// Per-edge: dedupe ownership via bitmap atomicOr, gather motif masks from
// dense A1/A2, count degrees for the two CSRs, flag motif endpoint nodes.
__global__ void __launch_bounds__(256) edge_classify(
        const int* __restrict__ src, const int* __restrict__ dst,
        const float* __restrict__ A1, const float* __restrict__ A2,
        unsigned* __restrict__ bitmap,
        int* __restrict__ srcCnt, int* __restrict__ dstCnt,
        unsigned char* __restrict__ nf1, unsigned char* __restrict__ nf2,
        unsigned char* __restrict__ eflags) {
    int i = blockIdx.x * blockDim.x + threadIdx.x;
    if (i >= E) return;
    int u = src[i], v = dst[i];
    long long key = ((long long)u << 13) | v;
    unsigned bit = 1u << (key & 31);
    unsigned old = atomicOr(&bitmap[key >> 5], bit);
    int own = ((old & bit) == 0) ? 1 : 0;
    float a1 = A1[key];
    float a2 = A2[key];
    int f1 = (a1 > 0.0f) ? 1 : 0;
    int f2 = (a2 > 0.0f) ? 1 : 0;
    eflags[i] = (unsigned char)(own | (f1 << 1) | (f2 << 2));
    if (own) atomicAdd(&srcCnt[u], 1);
    atomicAdd(&dstCnt[v], 1);
    if (f1) { nf1[u] = 1; nf1[v] = 1; }
    if (f2) { nf2[u] = 1; nf2[v] = 1; }
}

// Exclusive prefix scan of 8192 counts (one block per array).
__global__ void __launch_bounds__(256) scan2(
        const int* __restrict__ srcCnt, int* __restrict__ srcPtr, int* __restrict__ srcFill,
        const int* __restrict__ dstCnt, int* __restrict__ dstPtr, int* __restrict__ dstFill) {
    const int* cnt = (blockIdx.x == 0) ? srcCnt : dstCnt;
    int* ptr  = (blockIdx.x == 0) ? srcPtr : dstPtr;
    int* fill = (blockIdx.x == 0) ? srcFill : dstFill;
    __shared__ int ssum[256];
    int t = threadIdx.x;
    int base = t * 32;
    int loc[32];
    int s = 0;
    for (int j = 0; j < 32; ++j) { loc[j] = cnt[base + j]; s += loc[j]; }
    ssum[t] = s;
    __syncthreads();
    for (int off = 1; off < 256; off <<= 1) {
        int v = (t >= off) ? ssum[t - off] : 0;
        __syncthreads();
        ssum[t] += v;
        __syncthreads();
    }
    int ex = (t == 0) ? 0 : ssum[t - 1];
    for (int j = 0; j < 32; ++j) {
        ptr[base + j] = ex;
        fill[base + j] = ex;
        ex += loc[j];
    }
    if (t == 255) ptr[N] = ex;
}

// Scatter edges into src-CSR (owned only) and dst-CSR (all edges), flags packed.
__global__ void __launch_bounds__(256) csr_fill(
        const int* __restrict__ src, const int* __restrict__ dst,
        const unsigned char* __restrict__ eflags,
        int* __restrict__ srcFill, int* __restrict__ dstFill,
        int* __restrict__ csrS, int* __restrict__ csrD) {
    int i = blockIdx.x * blockDim.x + threadIdx.x;
    if (i >= E) return;
    int u = src[i], v = dst[i];
    int fl = eflags[i];
    int f12 = (fl >> 1) & 3;
    if (fl & 1) {
        int p = atomicAdd(&srcFill[u], 1);
        csrS[p] = v | (f12 << 13);
    }
    int p2 = atomicAdd(&dstFill[v], 1);
    csrD[p2] = u | (f12 << 13);
}

// Row pipeline 1: Ah = A@h (dedup CSR gather, 4-way ILP) -> Z = Ah@Ww^T + Wb
// -> ft0 = Z@fc0. One wave per row, lane = feature; Ah/Z stay in registers.
__global__ void __launch_bounds__(256) rowpipe1(
        const int* __restrict__ srcPtr, const int* __restrict__ csrS,
        const float* __restrict__ h, const float* __restrict__ Ww,
        const float* __restrict__ Wb, const float* __restrict__ fc0,
        float* __restrict__ Z, float* __restrict__ ft0) {
    __shared__ float W1[64 * 64];   // W1[k][j] = Ww[j][k]
    __shared__ float W2[64 * 64];   // W2[k][j] = fc0[k][j]
    int t = threadIdx.x;
    for (int i = t; i < 4096; i += 256) {
        int r = i >> 6, c = i & 63;
        W1[i] = Ww[c * 64 + r];
        W2[i] = fc0[i];
    }
    __syncthreads();
    int wid = t >> 6, lane = t & 63;
    int row = blockIdx.x * 4 + wid;
    int b = srcPtr[row], e = srcPtr[row + 1];
    float a0 = 0.0f, a1 = 0.0f, a2 = 0.0f, a3 = 0.0f;
    int j = b;
    for (; j + 3 < e; j += 4) {
        int u0 = csrS[j] & 8191, u1 = csrS[j + 1] & 8191;
        int u2 = csrS[j + 2] & 8191, u3 = csrS[j + 3] & 8191;
        a0 += h[(size_t)u0 * D + lane];
        a1 += h[(size_t)u1 * D + lane];
        a2 += h[(size_t)u2 * D + lane];
        a3 += h[(size_t)u3 * D + lane];
    }
    for (; j < e; ++j) a0 += h[(size_t)(csrS[j] & 8191) * D + lane];
    float ah = (a0 + a1) + (a2 + a3);
    float z = Wb[lane];
    #pragma unroll 8
    for (int k = 0; k < 64; ++k)
        z = fmaf(__shfl(ah, k), W1[k * 64 + lane], z);
    Z[(size_t)row * D + lane] = z;
    float f = 0.0f;
    #pragma unroll 8
    for (int k = 0; k < 64; ++k)
        f = fmaf(__shfl(z, k), W2[k * 64 + lane], f);
    ft0[(size_t)row * D + lane] = f;
}

// Row pipeline 2: az1 = A1@Z, az2 = A2@Z (flagged CSR gather, 2-way ILP)
// -> ft1 = az1@fc1, ft2 = az2@fc2.
__global__ void __launch_bounds__(256) rowpipe2(
        const int* __restrict__ srcPtr, const int* __restrict__ csrS,
        const float* __restrict__ Z,
        const float* __restrict__ fc1, const float* __restrict__ fc2,
        float* __restrict__ ft1, float* __restrict__ ft2) {
    __shared__ float W1[64 * 64];
    __shared__ float W2[64 * 64];
    int t = threadIdx.x;
    for (int i = t; i < 4096; i += 256) {
        W1[i] = fc1[i];
        W2[i] = fc2[i];
    }
    __syncthreads();
    int wid = t >> 6, lane = t & 63;
    int row = blockIdx.x * 4 + wid;
    int b = srcPtr[row], e = srcPtr[row + 1];
    float a1x = 0.0f, a2x = 0.0f, a1y = 0.0f, a2y = 0.0f;
    int j = b;
    for (; j + 1 < e; j += 2) {
        int e0 = csrS[j], e1 = csrS[j + 1];
        if (e0 >> 13) {
            float z = Z[(size_t)(e0 & 8191) * D + lane];
            if (e0 & (1 << 13)) a1x += z;
            if (e0 & (1 << 14)) a2x += z;
        }
        if (e1 >> 13) {
            float z = Z[(size_t)(e1 & 8191) * D + lane];
            if (e1 & (1 << 13)) a1y += z;
            if (e1 & (1 << 14)) a2y += z;
        }
    }
    for (; j < e; ++j) {
        int e0 = csrS[j];
        if (e0 >> 13) {
            float z = Z[(size_t)(e0 & 8191) * D + lane];
            if (e0 & (1 << 13)) a1x += z;
            if (e0 & (1 << 14)) a2x += z;
        }
    }
    float s1 = a1x + a1y, s2 = a2x + a2y;
    float f1 = 0.0f, f2 = 0.0f;
    #pragma unroll 8
    for (int k = 0; k < 64; ++k) {
        f1 = fmaf(__shfl(s1, k), W1[k * 64 + lane], f1);
        f2 = fmaf(__shfl(s2, k), W2[k * 64 + lane], f2);
    }
    ft1[(size_t)row * D + lane] = f1;
    ft2[(size_t)row * D + lane] = f2;
}

// Per-lane SDDMM for all 3 motifs: s_m = <ft_m[u], fv_m>/8 (fv via LDS bcast).
__device__ __forceinline__ void sddmm3(
        const float* __restrict__ ft0,
        const float4* __restrict__ fq0, const float4* __restrict__ fq1,
        const float4* __restrict__ fq2,
        int ent, bool valid, float& s0, float& s1, float& s2) {
    s0 = -3.0e38f; s1 = -3.0e38f; s2 = -3.0e38f;
    if (!valid) return;
    int u = ent & 8191;
    const float4* pu = (const float4*)(ft0 + (size_t)u * D);
    {
        float d0 = 0.0f, d1 = 0.0f;
        #pragma unroll
        for (int k = 0; k < 16; k += 2) {
            float4 a = pu[k], bq = fq0[k];
            float4 c = pu[k + 1], dq = fq0[k + 1];
            d0 = fmaf(a.x, bq.x, d0); d0 = fmaf(a.y, bq.y, d0);
            d0 = fmaf(a.z, bq.z, d0); d0 = fmaf(a.w, bq.w, d0);
            d1 = fmaf(c.x, dq.x, d1); d1 = fmaf(c.y, dq.y, d1);
            d1 = fmaf(c.z, dq.z, d1); d1 = fmaf(c.w, dq.w, d1);
        }
        s0 = (d0 + d1) * 0.125f;
    }
    if (ent & (1 << 13)) {
        const float4* p1 = pu + ND / 4;
        float d0 = 0.0f, d1 = 0.0f;
        #pragma unroll
        for (int k = 0; k < 16; k += 2) {
            float4 a = p1[k], bq = fq1[k];
            float4 c = p1[k + 1], dq = fq1[k + 1];
            d0 = fmaf(a.x, bq.x, d0); d0 = fmaf(a.y, bq.y, d0);
            d0 = fmaf(a.z, bq.z, d0); d0 = fmaf(a.w, bq.w, d0);
            d1 = fmaf(c.x, dq.x, d1); d1 = fmaf(c.y, dq.y, d1);
            d1 = fmaf(c.z, dq.z, d1); d1 = fmaf(c.w, dq.w, d1);
        }
        s1 = (d0 + d1) * 0.125f;
    }
    if (ent & (1 << 14)) {
        const float4* p2 = pu + 2 * (ND / 4);
        float d0 = 0.0f, d1 = 0.0f;
        #pragma unroll
        for (int k = 0; k < 16; k += 2) {
            float4 a = p2[k], bq = fq2[k];
            float4 c = p2[k + 1], dq = fq2[k + 1];
            d0 = fmaf(a.x, bq.x, d0); d0 = fmaf(a.y, bq.y, d0);
            d0 = fmaf(a.z, bq.z, d0); d0 = fmaf(a.w, bq.w, d0);
            d1 = fmaf(c.x, dq.x, d1); d1 = fmaf(c.y, dq.y, d1);
            d1 = fmaf(c.z, dq.z, d1); d1 = fmaf(c.w, dq.w, d1);
        }
        s2 = (d0 + d1) * 0.125f;
    }
}

// GAT scores+softmax only: per dst-row compute per-edge alpha for 3 motifs
// and scatter-add into beta[m][u] (global pooled aggregation is then a dense
// weighted row-sum). Scores kept in registers for rows <= 256 edges (always,
// for Poisson(64) degrees); recompute fallback beyond. lane = edge.
__global__ void __launch_bounds__(256) gat_alpha(
        const float* __restrict__ ftAll, const int* __restrict__ dstPtr,
        const int* __restrict__ csrD, float* __restrict__ beta) {
    int t = threadIdx.x, wid = t >> 6, lane = t & 63;
    int row = blockIdx.x * 4 + wid;
    __shared__ float fv[4][3][64];
    const float* ft0 = ftAll;
    fv[wid][0][lane] = ft0[(size_t)row * D + lane];
    fv[wid][1][lane] = ft0[ND + (size_t)row * D + lane];
    fv[wid][2][lane] = ft0[2 * ND + (size_t)row * D + lane];
    const float4* fq0 = (const float4*)fv[wid][0];
    const float4* fq1 = (const float4*)fv[wid][1];
    const float4* fq2 = (const float4*)fv[wid][2];
    int b = dstPtr[row], e = dstPtr[row + 1];
    int nch = (e - b + 63) >> 6;
    float w0r[4], w1r[4], w2r[4];
    int entr[4];
    float mr0 = -3.0e38f, mr1 = -3.0e38f, mr2 = -3.0e38f;
    // pass 1: scores (kept in regs) + exact segment max
    for (int c = 0; c < nch; ++c) {
        int j = b + c * 64 + lane;
        bool valid = j < e;
        int ent = valid ? (csrD[j] | (1 << 15)) : 0;
        float s0, s1, s2;
        sddmm3(ft0, fq0, fq1, fq2, ent, valid, s0, s1, s2);
        if (c < 4) { w0r[c] = s0; w1r[c] = s1; w2r[c] = s2; entr[c] = ent; }
        float c0 = s0, c1 = s1, c2 = s2;
        c0 = fmaxf(c0, __shfl_xor(c0, 1));  c1 = fmaxf(c1, __shfl_xor(c1, 1));  c2 = fmaxf(c2, __shfl_xor(c2, 1));
        c0 = fmaxf(c0, __shfl_xor(c0, 2));  c1 = fmaxf(c1, __shfl_xor(c1, 2));  c2 = fmaxf(c2, __shfl_xor(c2, 2));
        c0 = fmaxf(c0, __shfl_xor(c0, 4));  c1 = fmaxf(c1, __shfl_xor(c1, 4));  c2 = fmaxf(c2, __shfl_xor(c2, 4));
        c0 = fmaxf(c0, __shfl_xor(c0, 8));  c1 = fmaxf(c1, __shfl_xor(c1, 8));  c2 = fmaxf(c2, __shfl_xor(c2, 8));
        c0 = fmaxf(c0, __shfl_xor(c0, 16)); c1 = fmaxf(c1, __shfl_xor(c1, 16)); c2 = fmaxf(c2, __shfl_xor(c2, 16));
        c0 = fmaxf(c0, __shfl_xor(c0, 32)); c1 = fmaxf(c1, __shfl_xor(c1, 32)); c2 = fmaxf(c2, __shfl_xor(c2, 32));
        mr0 = fmaxf(mr0, c0); mr1 = fmaxf(mr1, c1); mr2 = fmaxf(mr2, c2);
    }
    // pass 2: w = exp(s - m) (regs), den = sum
    float den0 = 0.0f, den1 = 0.0f, den2 = 0.0f;
    for (int c = 0; c < nch; ++c) {
        float s0, s1, s2; int ent;
        if (c < 4) { s0 = w0r[c]; s1 = w1r[c]; s2 = w2r[c]; ent = entr[c]; }
        else {
            int j = b + c * 64 + lane;
            bool valid = j < e;
            ent = valid ? (csrD[j] | (1 << 15)) : 0;
            sddmm3(ft0, fq0, fq1, fq2, ent, valid, s0, s1, s2);
        }
        float w0 = (ent & (1 << 15)) ? __expf(s0 - mr0) : 0.0f;
        float w1 = (ent & (1 << 13)) ? __expf(s1 - mr1) : 0.0f;
        float w2 = (ent & (1 << 14)) ? __expf(s2 - mr2) : 0.0f;
        if (c < 4) { w0r[c] = w0; w1r[c] = w1; w2r[c] = w2; }
        float t0 = w0, t1 = w1, t2 = w2;
        t0 += __shfl_xor(t0, 1);  t1 += __shfl_xor(t1, 1);  t2 += __shfl_xor(t2, 1);
        t0 += __shfl_xor(t0, 2);  t1 += __shfl_xor(t1, 2);  t2 += __shfl_xor(t2, 2);
        t0 += __shfl_xor(t0, 4);  t1 += __shfl_xor(t1, 4);  t2 += __shfl_xor(t2, 4);
        t0 += __shfl_xor(t0, 8);  t1 += __shfl_xor(t1, 8);  t2 += __shfl_xor(t2, 8);
        t0 += __shfl_xor(t0, 16); t1 += __shfl_xor(t1, 16); t2 += __shfl_xor(t2, 16);
        t0 += __shfl_xor(t0, 32); t1 += __shfl_xor(t1, 32); t2 += __shfl_xor(t2, 32);
        den0 += t0; den1 += t1; den2 += t2;
    }
    float i0 = 1.0f / fmaxf(den0, 1e-9f);
    float i1 = 1.0f / fmaxf(den1, 1e-9f);
    float i2 = 1.0f / fmaxf(den2, 1e-9f);
    // pass 3: alpha scatter into beta
    for (int c = 0; c < nch; ++c) {
        float w0, w1, w2; int ent;
        if (c < 4) { w0 = w0r[c]; w1 = w1r[c]; w2 = w2r[c]; ent = entr[c]; }
        else {
            int j = b + c * 64 + lane;
            bool valid = j < e;
            ent = valid ? (csrD[j] | (1 << 15)) : 0;
            float s0, s1, s2;
            sddmm3(ft0, fq0, fq1, fq2, ent, valid, s0, s1, s2);
            w0 = (ent & (1 << 15)) ? __expf(s0 - mr0) : 0.0f;
            w1 = (ent & (1 << 13)) ? __expf(s1 - mr1) : 0.0f;
            w2 = (ent & (1 << 14)) ? __expf(s2 - mr2) : 0.0f;
        }
        int u = ent & 8191;
        if (w0 > 0.0f) atomicAdd(&beta[u], w0 * i0);
        if (w1 > 0.0f) atomicAdd(&beta[N + u], w1 * i1);
        if (w2 > 0.0f) atomicAdd(&beta[2 * N + u], w2 * i2);
    }
}

// pooled[m][i] = sum_u beta[m][u] * ft[m][u][i]  (dense, coalesced).
__global__ void __launch_bounds__(256) pool_dense(
        const float* __restrict__ ftAll, const float* __restrict__ beta,
        float* __restrict__ pooled) {
    int t = threadIdx.x, wid = t >> 6, lane = t & 63;
    float a0 = 0.0f, a1 = 0.0f, a2 = 0.0f;
    for (int u = blockIdx.x * 4 + wid; u < N; u += gridDim.x * 4) {
        float b0 = beta[u], b1 = beta[N + u], b2 = beta[2 * N + u];
        const float* p = ftAll + (size_t)u * D + lane;
        a0 = fmaf(b0, p[0], a0);
        a1 = fmaf(b1, p[ND], a1);
        a2 = fmaf(b2, p[2 * ND], a2);
    }
    __shared__ float red[3][256];
    red[0][t] = a0; red[1][t] = a1; red[2][t] = a2;
    __syncthreads();
    if (wid < 3) {
        float s = red[wid][lane] + red[wid][64 + lane] + red[wid][128 + lane] + red[wid][192 + lane];
        atomicAdd(&pooled[wid * 64 + lane], s);
    }
}

// Final: motif node counts, divide pooled sums, 192x2 linear.
__global__ void __launch_bounds__(256) final_kernel(
        const float* __restrict__ pooled,
        const unsigned char* __restrict__ nf1, const unsigned char* __restrict__ nf2,
        const float* __restrict__ lin_w, const float* __restrict__ lin_b,
        float* __restrict__ out) {
    __shared__ int r1[256], r2[256];
    __shared__ float feat[192];
    __shared__ int cnt[2];
    int t = threadIdx.x;
    int s1 = 0, s2 = 0;
    for (int i = t; i < N; i += 256) { s1 += nf1[i]; s2 += nf2[i]; }
    r1[t] = s1; r2[t] = s2;
    __syncthreads();
    for (int off = 128; off > 0; off >>= 1) {
        if (t < off) { r1[t] += r1[t + off]; r2[t] += r2[t + off]; }
        __syncthreads();
    }
    if (t == 0) { cnt[0] = r1[0]; cnt[1] = r2[0]; }
    __syncthreads();
    if (t < 192) {
        int sel = t >> 6;
        float div = (sel == 0) ? (float)N : fmaxf((float)cnt[sel - 1], 1.0f);
        feat[t] = pooled[t] / div;
    }
    __syncthreads();
    if (t < 2) {
        float o = lin_b[t];
        for (int k = 0; k < 192; ++k) o = fmaf(feat[k], lin_w[k * 2 + t], o);
        out[t] = o;
    }
}

// ---------------- launch ----------------
extern "C" void kernel_launch(void* const* d_in, const int* in_sizes, int n_in,
                              void* d_out, int out_size, void* d_ws, size_t ws_size,
                              hipStream_t stream) {
    const float* h   = (const float*)d_in[0];
    // d_in[1] (dense A) never read: structure == edge list, values == 1.
    const float* A1  = (const float*)d_in[2];
    const float* A2  = (const float*)d_in[3];
    const float* Ww  = (const float*)d_in[4];
    const float* Wb  = (const float*)d_in[5];
    const float* fc0 = (const float*)d_in[6];
    const float* fc1 = (const float*)d_in[7];
    const float* fc2 = (const float*)d_in[8];
    const float* lw  = (const float*)d_in[9];
    const float* lb  = (const float*)d_in[10];
    const int* src   = (const int*)d_in[11];
    const int* dst   = (const int*)d_in[12];
    float* out = (float*)d_out;

    char* w = (char*)d_ws;
    unsigned* bitmap   = (unsigned*)(w + O_BITMAP);
    int* srcCnt        = (int*)(w + O_SRCCNT);
    int* dstCnt        = (int*)(w + O_DSTCNT);
    unsigned char* nf1 = (unsigned char*)(w + O_NF1);
    unsigned char* nf2 = (unsigned char*)(w + O_NF2);
    float* pooled      = (float*)(w + O_POOLED);
    float* beta        = (float*)(w + O_BETA);
    int* srcPtr        = (int*)(w + O_SRCPTR);
    int* dstPtr        = (int*)(w + O_DSTPTR);
    int* srcFill       = (int*)(w + O_SRCFILL);
    int* dstFill       = (int*)(w + O_DSTFILL);
    unsigned char* efl = (unsigned char*)(w + O_EFLAGS);
    int* csrS          = (int*)(w + O_CSRS);
    int* csrD          = (int*)(w + O_CSRD);
    float* Z           = (float*)(w + O_Z);
    float* ftAll       = (float*)(w + O_FT);
    float* ft1         = ftAll + (size_t)ND;
    float* ft2         = ftAll + 2 * (size_t)ND;

    hipMemsetAsync(w, 0, ZERO_END, stream);

    edge_classify<<<E / 256, 256, 0, stream>>>(src, dst, A1, A2, bitmap, srcCnt, dstCnt, nf1, nf2, efl);
    scan2<<<2, 256, 0, stream>>>(srcCnt, srcPtr, srcFill, dstCnt, dstPtr, dstFill);
    csr_fill<<<E / 256, 256, 0, stream>>>(src, dst, efl, srcFill, dstFill, csrS, csrD);

    rowpipe1<<<N / 4, 256, 0, stream>>>(srcPtr, csrS, h, Ww, Wb, fc0, Z, ftAll);
    rowpipe2<<<N / 4, 256, 0, stream>>>(srcPtr, csrS, Z, fc1, fc2, ft1, ft2);

    gat_alpha<<<N / 4, 256, 0, stream>>>(ftAll, dstPtr, csrD, beta);
    pool_dense<<<256, 256, 0, stream>>>(ftAll, beta, pooled);

    final_kernel<<<1, 256, 0, stream>>>(pooled, nf1, nf2, lw, lb, out);
}